// Round 8
// baseline (69.879 us; speedup 1.0000x reference)
//
#include <hip/hip_runtime.h>

// Sinkhorn loss, v8 — ONE WAVE PER BATCH, zero LDS, zero barriers.
// 16 blocks x 64 threads; the whole 48x48 state lives in one wave's
// registers (9 MFMA 16x16 tiles, C-layout; 36 f32/lane). All cross-lane
// exchange is __shfl (ds_bpermute) — no __syncthreads anywhere.
//
// Key identities:
//  * A-frag(M) == B-frag(M^T) as register contents, so with
//      stage1: Z = W^T @ T      (A via 4-shfl gather of packed W)
//      stage2: S = Z^T @ T      (A via 4-shfl gather of packed Z)
//    we get S = (W^T T)^T T = T W T exactly — no transposes needed.
//  * Gather garbage for k in [48,64) is killed by zeroed T-const frags.
//  * 100*EPS == 1  =>  w' = w * mu / (w*S + 1e-6): no log/exp in loop.
//  * Transposed-slot convention (as v5): lane slot (i,j,rg) holds logical
//    element (row = j*16+n15, col = i*16+quad*4+rg) -> coalesced float4
//    input loads; T W T is transpose-equivariant so orientation stays
//    consistent; final total sum is orientation-free.

#define POISON 0xAAAAAAAAu

typedef __attribute__((ext_vector_type(8))) short short8;
typedef __attribute__((ext_vector_type(4))) float f32x4;
typedef unsigned int uint;

__device__ __forceinline__ f32x4 mm16(short8 a, short8 b, f32x4 c) {
    return __builtin_amdgcn_mfma_f32_16x16x32_bf16(a, b, c, 0, 0, 0);
}
__device__ __forceinline__ uint fbits(float x) { union { float f; uint u; } c; c.f = x; return c.u; }
__device__ __forceinline__ float ffloat(uint x) { union { uint u; float f; } c; c.u = x; return c.f; }

// pack two f32 into b32: low16 = bf16trunc(a), high16 = bf16trunc(b)
__device__ __forceinline__ uint pack2(float a, float b) {
    return (fbits(b) & 0xffff0000u) | (fbits(a) >> 16);
}
// round f32 to nearest bf16, keep as f32 (makes later pack2 exact)
__device__ __forceinline__ float bfr(float x) {
    uint u = fbits(x);
    u = (u + 0x7fffu + ((u >> 16) & 1u)) & 0xffff0000u;
    return ffloat(u);
}
__device__ __forceinline__ uint shflu(uint v, int lane) {
    return (uint)__shfl((int)v, lane, 64);
}

// B-frag of the 48x48 matrix whose packed C-layout tiles are P[ti][tj][r]:
// s[j] = M[ch*32 + quad*8 + j][cb*16 + n15].  (Also serves as A-frag of M^T.)
// ch==1 rows >=48 return garbage for quads 2,3 — killed by zeroed T consts.
__device__ __forceinline__ short8 bgather(const uint (&P)[3][3][2], int ch, int cb,
                                          int addr_a, int addr_b, bool hiq) {
    uint g0, g1, g2, g3;
    if (ch == 0) {
        uint a0 = shflu(P[0][cb][0], addr_a), b0 = shflu(P[1][cb][0], addr_a);
        uint a1 = shflu(P[0][cb][1], addr_a), b1 = shflu(P[1][cb][1], addr_a);
        uint a2 = shflu(P[0][cb][0], addr_b), b2 = shflu(P[1][cb][0], addr_b);
        uint a3 = shflu(P[0][cb][1], addr_b), b3 = shflu(P[1][cb][1], addr_b);
        g0 = hiq ? b0 : a0; g1 = hiq ? b1 : a1;
        g2 = hiq ? b2 : a2; g3 = hiq ? b3 : a3;
    } else {
        g0 = shflu(P[2][cb][0], addr_a);
        g1 = shflu(P[2][cb][1], addr_a);
        g2 = shflu(P[2][cb][0], addr_b);
        g3 = shflu(P[2][cb][1], addr_b);
    }
    union { uint u[4]; short8 s; } cv;
    cv.u[0] = g0; cv.u[1] = g1; cv.u[2] = g2; cv.u[3] = g3;
    return cv.s;
}

__global__ __launch_bounds__(64, 1) void sinkhorn_kernel(const float* __restrict__ y,
                                                         const float* __restrict__ yt,
                                                         unsigned* __restrict__ parts,
                                                         unsigned* __restrict__ ctr,
                                                         float* __restrict__ out)
{
    const int t = threadIdx.x;
    const int b = blockIdx.x;
    const int quad = t >> 4;
    const int n15  = t & 15;
    const bool hiq = quad >= 2;
    const int addr_a = 32 * (quad & 1) + n15;   // owner quad 2*(quad&1), col n15
    const int addr_b = addr_a + 16;

    // ---- input loads first (coalesced float4 at transposed slots) ----
    f32x4 yv[3][3], ytv[3][3];
#pragma unroll
    for (int i = 0; i < 3; ++i)
#pragma unroll
        for (int j = 0; j < 3; ++j) {
            int off = b * 2304 + (j * 16 + n15) * 48 + i * 16 + quad * 4;
            yv[i][j]  = *(const f32x4*)(y  + off);
            ytv[i][j] = *(const f32x4*)(yt + off);
        }

    // ---- per-lane Gaussian table: g(d), td(d) for d = lane index ----
    float dl  = (float)t * (1.0f / 48.0f);
    float ds2 = dl * dl;
    float ev  = __expf(-100.0f * ds2);
    float gv  = bfr(ev);          // T entry, bf16-rounded
    float tdv = bfr(ev * ds2);    // T*dsq entry, bf16-rounded

    // ---- T const frags TC[blk][ch]: s[j] = T[blk*16+n15][ch*32+quad*8+j],
    //      zeroed for k >= 48 (this zeroing also kills gather garbage) ----
    short8 TC[3][2];
#pragma unroll
    for (int blk = 0; blk < 3; ++blk)
#pragma unroll
        for (int ch = 0; ch < 2; ++ch) {
            uint w[4];
#pragma unroll
            for (int p = 0; p < 4; ++p) {
                int k0 = ch * 32 + quad * 8 + 2 * p;
                int r  = blk * 16 + n15;
                float g0 = __shfl(gv, abs(r - k0), 64);
                float g1 = __shfl(gv, abs(r - k0 - 1), 64);
                g0 = (k0     < 48) ? g0 : 0.f;
                g1 = (k0 + 1 < 48) ? g1 : 0.f;
                w[p] = pack2(g0, g1);
            }
            union { uint u[4]; short8 s; } cv;
            cv.u[0]=w[0]; cv.u[1]=w[1]; cv.u[2]=w[2]; cv.u[3]=w[3];
            TC[blk][ch] = cv.s;
        }

    // ---- masses -> mu, nu (slots local to lane) ----
    float mu[3][3][4], nu[3][3][4];
    float sx = 0.f, sy = 0.f;
#pragma unroll
    for (int i = 0; i < 3; ++i)
#pragma unroll
        for (int j = 0; j < 3; ++j)
#pragma unroll
            for (int rg = 0; rg < 4; ++rg) {
                float a = fminf(fmaxf(yv[i][j][rg],  0.f), 1e9f) + 1e-9f;
                float c = fminf(fmaxf(ytv[i][j][rg], 0.f), 1e9f) + 1e-9f;
                mu[i][j][rg] = a; nu[i][j][rg] = c;
                sx += a; sy += c;
            }
#pragma unroll
    for (int off = 1; off < 64; off <<= 1) {
        sx += __shfl_xor(sx, off, 64);
        sy += __shfl_xor(sy, off, 64);
    }
    const float rsx = 1.0f / sx, rsy = 1.0f / sy;
#pragma unroll
    for (int i = 0; i < 3; ++i)
#pragma unroll
        for (int j = 0; j < 3; ++j)
#pragma unroll
            for (int rg = 0; rg < 4; ++rg) { mu[i][j][rg] *= rsx; nu[i][j][rg] *= rsy; }

    // ---- state: wu, wv (f32) + packed bf16 copies for the matmuls ----
    float wu[3][3][4], wv[3][3][4];
    uint Wup[3][3][2], Wvp[3][3][2];
#pragma unroll
    for (int i = 0; i < 3; ++i)
#pragma unroll
        for (int j = 0; j < 3; ++j) {
#pragma unroll
            for (int rg = 0; rg < 4; ++rg) { wu[i][j][rg] = 1.f; wv[i][j][rg] = 1.f; }
            Wup[i][j][0] = 0x3F803F80u; Wup[i][j][1] = 0x3F803F80u;
            Wvp[i][j][0] = 0x3F803F80u; Wvp[i][j][1] = 0x3F803F80u;
        }

    const f32x4 zz = {0.f, 0.f, 0.f, 0.f};

    // one half-iteration: S = T*(field)*T; w' = w*m/(w*S+1e-6); repack dst
    auto half_iter = [&](float (&w)[3][3][4], const float (&m)[3][3][4],
                         const uint (&srcP)[3][3][2], uint (&dstP)[3][3][2]) {
        f32x4 Z[3][3];
#pragma unroll
        for (int i = 0; i < 3; ++i)
#pragma unroll
            for (int j = 0; j < 3; ++j) Z[i][j] = zz;
#pragma unroll
        for (int ch = 0; ch < 2; ++ch) {
            short8 Af[3];
#pragma unroll
            for (int cb = 0; cb < 3; ++cb) Af[cb] = bgather(srcP, ch, cb, addr_a, addr_b, hiq);
#pragma unroll
            for (int i = 0; i < 3; ++i)
#pragma unroll
                for (int j = 0; j < 3; ++j) Z[i][j] = mm16(Af[i], TC[j][ch], Z[i][j]);
        }
        uint Zp[3][3][2];
#pragma unroll
        for (int i = 0; i < 3; ++i)
#pragma unroll
            for (int j = 0; j < 3; ++j) {
                Zp[i][j][0] = pack2(Z[i][j][0], Z[i][j][1]);
                Zp[i][j][1] = pack2(Z[i][j][2], Z[i][j][3]);
            }
        f32x4 S[3][3];
#pragma unroll
        for (int i = 0; i < 3; ++i)
#pragma unroll
            for (int j = 0; j < 3; ++j) S[i][j] = zz;
#pragma unroll
        for (int ch = 0; ch < 2; ++ch) {
            short8 Ag[3];
#pragma unroll
            for (int cb = 0; cb < 3; ++cb) Ag[cb] = bgather(Zp, ch, cb, addr_a, addr_b, hiq);
#pragma unroll
            for (int i = 0; i < 3; ++i)
#pragma unroll
                for (int j = 0; j < 3; ++j) S[i][j] = mm16(Ag[i], TC[j][ch], S[i][j]);
        }
#pragma unroll
        for (int i = 0; i < 3; ++i)
#pragma unroll
            for (int j = 0; j < 3; ++j) {
#pragma unroll
                for (int rg = 0; rg < 4; ++rg) {
                    float ww = w[i][j][rg];
                    float dn = fmaf(ww, S[i][j][rg], 1e-6f);
                    w[i][j][rg] = ww * m[i][j][rg] * __builtin_amdgcn_rcpf(dn);
                }
                dstP[i][j][0] = pack2(w[i][j][0], w[i][j][1]);
                dstP[i][j][1] = pack2(w[i][j][2], w[i][j][3]);
            }
    };

    for (int it = 0; it < 5; ++it) {
        half_iter(wu, mu, Wvp, Wup);   // u-update: field = exp(v/eps)
        half_iter(wv, nu, Wup, Wvp);   // v-update: field = exp(u/eps)
    }

    // ---- TD const frags (epilogue only) ----
    short8 TD[3][2];
#pragma unroll
    for (int blk = 0; blk < 3; ++blk)
#pragma unroll
        for (int ch = 0; ch < 2; ++ch) {
            uint w[4];
#pragma unroll
            for (int p = 0; p < 4; ++p) {
                int k0 = ch * 32 + quad * 8 + 2 * p;
                int r  = blk * 16 + n15;
                float g0 = __shfl(tdv, abs(r - k0), 64);
                float g1 = __shfl(tdv, abs(r - k0 - 1), 64);
                g0 = (k0     < 48) ? g0 : 0.f;
                g1 = (k0 + 1 < 48) ? g1 : 0.f;
                w[p] = pack2(g0, g1);
            }
            union { uint u[4]; short8 s; } cv;
            cv.u[0]=w[0]; cv.u[1]=w[1]; cv.u[2]=w[2]; cv.u[3]=w[3];
            TD[blk][ch] = cv.s;
        }

    // ---- final cost: G = TD*Wv*T + T*Wv*TD;  cost = sum wu .* G ----
    f32x4 Z1[3][3], Z2[3][3];
#pragma unroll
    for (int i = 0; i < 3; ++i)
#pragma unroll
        for (int j = 0; j < 3; ++j) { Z1[i][j] = zz; Z2[i][j] = zz; }
#pragma unroll
    for (int ch = 0; ch < 2; ++ch) {
        short8 Af[3];
#pragma unroll
        for (int cb = 0; cb < 3; ++cb) Af[cb] = bgather(Wvp, ch, cb, addr_a, addr_b, hiq);
#pragma unroll
        for (int i = 0; i < 3; ++i)
#pragma unroll
            for (int j = 0; j < 3; ++j) {
                Z1[i][j] = mm16(Af[i], TC[j][ch], Z1[i][j]);   // Wv^T @ T
                Z2[i][j] = mm16(Af[i], TD[j][ch], Z2[i][j]);   // Wv^T @ TD
            }
    }
    uint Z1p[3][3][2], Z2p[3][3][2];
#pragma unroll
    for (int i = 0; i < 3; ++i)
#pragma unroll
        for (int j = 0; j < 3; ++j) {
            Z1p[i][j][0] = pack2(Z1[i][j][0], Z1[i][j][1]);
            Z1p[i][j][1] = pack2(Z1[i][j][2], Z1[i][j][3]);
            Z2p[i][j][0] = pack2(Z2[i][j][0], Z2[i][j][1]);
            Z2p[i][j][1] = pack2(Z2[i][j][2], Z2[i][j][3]);
        }
    f32x4 G[3][3];
#pragma unroll
    for (int i = 0; i < 3; ++i)
#pragma unroll
        for (int j = 0; j < 3; ++j) G[i][j] = zz;
#pragma unroll
    for (int ch = 0; ch < 2; ++ch) {
        short8 A1[3], A2[3];
#pragma unroll
        for (int cb = 0; cb < 3; ++cb) {
            A1[cb] = bgather(Z1p, ch, cb, addr_a, addr_b, hiq);
            A2[cb] = bgather(Z2p, ch, cb, addr_a, addr_b, hiq);
        }
#pragma unroll
        for (int i = 0; i < 3; ++i)
#pragma unroll
            for (int j = 0; j < 3; ++j) {
                G[i][j] = mm16(A2[i], TC[j][ch], G[i][j]);   // (Wv^T TD)^T T = TD Wv T
                G[i][j] = mm16(A1[i], TD[j][ch], G[i][j]);   // (Wv^T T)^T TD = T Wv TD
            }
    }
    float local = 0.f;
#pragma unroll
    for (int i = 0; i < 3; ++i)
#pragma unroll
        for (int j = 0; j < 3; ++j)
#pragma unroll
            for (int rg = 0; rg < 4; ++rg)
                local = fmaf(wu[i][j][rg], G[i][j][rg], local);
#pragma unroll
    for (int off = 32; off > 0; off >>= 1) local += __shfl_down(local, off, 64);

    // ---- arrival-counter finish (v7): no polling, no extra dispatch ----
    if (t == 0) {
        __hip_atomic_store(&parts[b], fbits(local), __ATOMIC_RELEASE,
                           __HIP_MEMORY_SCOPE_AGENT);
        unsigned old = __hip_atomic_fetch_add(ctr, 1u, __ATOMIC_ACQ_REL,
                                              __HIP_MEMORY_SCOPE_AGENT);
        if (old == POISON + 15u) {      // last arriver
            float tot = 0.f;
#pragma unroll
            for (int i = 0; i < 16; ++i)
                tot += ffloat(__hip_atomic_load(&parts[i], __ATOMIC_RELAXED,
                                                __HIP_MEMORY_SCOPE_AGENT));
            out[0] = tot * (1.0f / 16.0f);
        }
    }
}

extern "C" void kernel_launch(void* const* d_in, const int* in_sizes, int n_in,
                              void* d_out, int out_size, void* d_ws, size_t ws_size,
                              hipStream_t stream)
{
    (void)in_sizes; (void)n_in; (void)ws_size; (void)out_size;
    const float* y  = (const float*)d_in[0];
    const float* yt = (const float*)d_in[1];
    unsigned* parts = (unsigned*)d_ws;             // ws[0..15], 0xAA-poisoned
    unsigned* ctr   = (unsigned*)d_ws + 16;        // ws[16], poison = initial
    float*    out   = (float*)d_out;

    sinkhorn_kernel<<<16, 64, 0, stream>>>(y, yt, parts, ctr, out);
}

// Round 9
// 67.282 us; speedup vs baseline: 1.0386x; 1.0386x over previous
//
#include <hip/hip_runtime.h>

// Sinkhorn loss, fully fused, MFMA edition v9 == v5 (best measured: 67.28 µs).
// One block per batch (b=16), n=48x48=2304, 5 iterations, single dispatch.
//
// Structure (why this exact shape — see session journal R2..R8):
//  - 9 waves per block, one 16x16 MFMA tile each; S = T @ W @ T per
//    half-iteration as two 48x48x48 stages. 9 co-resident waves hide
//    LDS/MFMA latency (R8 showed 1-wave shfl version is latency-bound: 43 µs).
//  - LDS data rides the MFMA A-slot; constant T/TD fragments ride the B-slot
//    (T symmetric => same registers serve either slot). Every stage stores
//    its result TRANSPOSED => each lane's 4 C/D elements are contiguous:
//    one ds_write_b64. Double-transpose per contraction restores orientation.
//  - T/TD fragments in registers, hi/lo bf16 split (fp32-grade, absmax 0.0).
//  - 100*EPS == 1  =>  w' = w * mu / (w*S + 1e-6): no log/exp in the loop.
//  - Finish: blocks 1..15 release partial+flag into 0xAA-poisoned d_ws;
//    block 0 polls the 15 flags IN PARALLEL (one lane per flag + shuffle).

#define TPB 576      // 9 waves = 9 MFMA tiles of 16x16 = 48x48
#define STRIDE 72    // shorts per LDS matrix row (144 B, 16B-aligned frags)
#define FLAG_MAGIC 0x5CA1AB1Eu

typedef __attribute__((ext_vector_type(8))) short short8;
typedef __attribute__((ext_vector_type(4))) short short4v;
typedef __attribute__((ext_vector_type(4))) float f32x4;

__device__ __forceinline__ void splitb(float x, short& hi, short& lo) {
    union { float f; unsigned u; } a, h;
    a.f = x;
    h.u = a.u & 0xffff0000u;          // truncate; lo captures residual
    hi  = (short)(h.u >> 16);
    union { float f; unsigned u; } l;
    l.f = x - h.f;
    lo  = (short)(l.u >> 16);
}

__device__ __forceinline__ short bf16rne(float x) {
    union { float f; unsigned u; } a;
    a.f = x;
    unsigned r = a.u + 0x7fffu + ((a.u >> 16) & 1u);
    return (short)(r >> 16);
}

__device__ __forceinline__ f32x4 mm16(short8 a, short8 b, f32x4 c) {
    return __builtin_amdgcn_mfma_f32_16x16x32_bf16(a, b, c, 0, 0, 0);
}

__global__ __launch_bounds__(TPB) void sinkhorn_kernel(const float* __restrict__ y,
                                                       const float* __restrict__ yt,
                                                       unsigned* __restrict__ flags,
                                                       float* __restrict__ parts,
                                                       float* __restrict__ out)
{
    __shared__ __align__(16) short sW [48 * STRIDE];  // current W (row-major)
    __shared__ __align__(16) short sP [48 * STRIDE];  // stage-1 out (transposed)
    __shared__ __align__(16) short sP2[48 * STRIDE];  // final-cost second buf
    __shared__ float red[32];

    const int t    = threadIdx.x;
    const int b    = blockIdx.x;
    const int lane = t & 63;
    const int wid  = t >> 6;            // wave id 0..8
    const int tr   = wid / 3;           // tile row
    const int tc   = wid - tr * 3;      // tile col
    const int n15  = lane & 15;
    const int quad = lane >> 4;
    const int kq   = quad * 8;
    const int r0   = tr * 16 + quad * 4;   // C/D row base
    const int c    = tc * 16 + n15;        // C/D col; also T-register row
    const int aBase  = (tr * 16 + n15) * STRIDE;      // A-frag row base (LDS)
    const int stBase = c * STRIDE + r0;               // transpose-store base
    // lane's elementwise slots: logical (c, r0+rg), rg = 0..3

    // ---- global input loads FIRST (float4; hide cold-miss under exp init) ----
    const f32x4 y4  = *(const f32x4*)(y  + b * 2304 + c * 48 + r0);
    const f32x4 yt4 = *(const f32x4*)(yt + b * 2304 + c * 48 + r0);

    // ---- T / TD register fragments, row c, hi/lo bf16 split (B-slot use) ----
    short8 Th0, Th1, Tl0, Tl1, Dh0, Dh1, Dl0, Dl1;
    {
        const float gm = (float)c / 48.0f;
#pragma unroll
        for (int kk = 0; kk < 8; ++kk) {
            int k0 = kq + kk;
            float d = gm - (float)k0 / 48.0f;
            float dsq = d * d;
            float e = __expf(-100.0f * dsq);
            short h, l;
            splitb(e, h, l);        Th0[kk] = h; Tl0[kk] = l;
            splitb(e * dsq, h, l);  Dh0[kk] = h; Dl0[kk] = l;
            int k1 = k0 + 32;
            if (k1 < 48) {
                float d1 = gm - (float)k1 / 48.0f;
                float q1 = d1 * d1;
                float e1 = __expf(-100.0f * q1);
                splitb(e1, h, l);       Th1[kk] = h; Tl1[kk] = l;
                splitb(e1 * q1, h, l);  Dh1[kk] = h; Dl1[kk] = l;
            } else {
                Th1[kk] = 0; Tl1[kk] = 0; Dh1[kk] = 0; Dl1[kk] = 0;
            }
        }
    }

    // ---- init LDS via short8 chunks: 9 chunks/row; 0..5 body, 6..8 K-pad ----
    if (t < 432) {
        const short8 zer  = {0, 0, 0, 0, 0, 0, 0, 0};
        const short  o    = (short)0x3F80;
        const short8 ones = {o, o, o, o, o, o, o, o};
        int ccol = t % 9;
        ((short8*)sW)[t] = (ccol < 6) ? ones : zer;   // W = exp(v/eps) = 1
        if (ccol >= 6) {                               // pads only; body is
            ((short8*)sP )[t] = zer;                   // overwritten pre-read
            ((short8*)sP2)[t] = zer;
        }
    }

    // ---- masses at slots (c, r0+rg) ----
    float mx[4], my[4];
#pragma unroll
    for (int rg = 0; rg < 4; ++rg) {
        mx[rg] = fminf(fmaxf(y4[rg],  0.f), 1e9f) + 1e-9f;
        my[rg] = fminf(fmaxf(yt4[rg], 0.f), 1e9f) + 1e-9f;
    }
    float sx = mx[0] + mx[1] + mx[2] + mx[3];
    float sy = my[0] + my[1] + my[2] + my[3];
#pragma unroll
    for (int off = 32; off > 0; off >>= 1) {
        sx += __shfl_down(sx, off);
        sy += __shfl_down(sy, off);
    }
    if (lane == 0) { red[wid] = sx; red[16 + wid] = sy; }
    __syncthreads();   // also covers LDS init above
    float ax = 0.f, ay = 0.f;
#pragma unroll
    for (int w = 0; w < TPB / 64; ++w) { ax += red[w]; ay += red[16 + w]; }
    const float rsx = 1.0f / ax, rsy = 1.0f / ay;

    float mu_[4], nu_[4];
#pragma unroll
    for (int q = 0; q < 4; ++q) { mu_[q] = mx[q] * rsx; nu_[q] = my[q] * rsy; }

    float wu_[4] = {1, 1, 1, 1}, wv_[4] = {1, 1, 1, 1};  // exp(u/eps), exp(v/eps)

    const f32x4 zz = {0.f, 0.f, 0.f, 0.f};

    // ---- 10 half-iterations: u-update (even) / v-update (odd) ----
    for (int half = 0; half < 10; ++half) {
        // stage 1: D1 = W @ T; store D1^T (b64)
        {
            short8 a0 = *(const short8*)(sW + aBase + kq);
            short8 a1 = *(const short8*)(sW + aBase + kq + 32);
            f32x4 x  = mm16(a0, Th0, zz);
            f32x4 yy = mm16(a1, Th1, zz);
            x  = mm16(a0, Tl0, x);
            yy = mm16(a1, Tl1, yy);
            f32x4 p = x + yy;
            short4v pk;
#pragma unroll
            for (int rg = 0; rg < 4; ++rg) pk[rg] = bf16rne(p[rg]);
            *(short4v*)(sP + stBase) = pk;
        }
        __syncthreads();
        // stage 2: D2 = (D1^T) @ T = S^T at slots; update state; store W' (b64)
        {
            short8 a0 = *(const short8*)(sP + aBase + kq);
            short8 a1 = *(const short8*)(sP + aBase + kq + 32);
            f32x4 x  = mm16(a0, Th0, zz);
            f32x4 yy = mm16(a1, Th1, zz);
            x  = mm16(a0, Tl0, x);
            yy = mm16(a1, Tl1, yy);
            f32x4 S = x + yy;          // S at logical (c, r0+rg)
            float* wc       = ((half & 1) == 0) ? wu_ : wv_;
            const float* m_ = ((half & 1) == 0) ? mu_ : nu_;
            short4v wk;
#pragma unroll
            for (int q = 0; q < 4; ++q) {
                // 100*eps == 1:  w' = e^{u'/eps} = w * mu / (w*S + 1e-6)
                wc[q] = wc[q] * m_[q] / (wc[q] * S[q] + 1e-6f);
                wk[q] = bf16rne(wc[q]);
            }
            *(short4v*)(sW + stBase) = wk;
        }
        __syncthreads();
    }

    // ---- final cost: G = TD@Wv@T + T@Wv@TD, cost = sum wu .* G ----
    {
        short8 a0 = *(const short8*)(sW + aBase + kq);
        short8 a1 = *(const short8*)(sW + aBase + kq + 32);
        f32x4 x1 = mm16(a0, Th0, zz), w1 = mm16(a1, Th1, zz);
        x1 = mm16(a0, Tl0, x1);  w1 = mm16(a1, Tl1, w1);
        f32x4 p1 = x1 + w1;                       // Wv @ T
        f32x4 x2 = mm16(a0, Dh0, zz), w2 = mm16(a1, Dh1, zz);
        x2 = mm16(a0, Dl0, x2);  w2 = mm16(a1, Dl1, w2);
        f32x4 p2 = x2 + w2;                       // Wv @ TD
        short4v k1, k2;
#pragma unroll
        for (int rg = 0; rg < 4; ++rg) { k1[rg] = bf16rne(p1[rg]); k2[rg] = bf16rne(p2[rg]); }
        *(short4v*)(sP  + stBase) = k1;
        *(short4v*)(sP2 + stBase) = k2;
    }
    __syncthreads();
    float local;
    {
        short8 a0 = *(const short8*)(sP  + aBase + kq);
        short8 a1 = *(const short8*)(sP  + aBase + kq + 32);
        short8 c0 = *(const short8*)(sP2 + aBase + kq);
        short8 c1 = *(const short8*)(sP2 + aBase + kq + 32);
        f32x4 x  = mm16(a0, Dh0, zz), yy = mm16(a1, Dh1, zz);
        x  = mm16(a0, Dl0, x);   yy = mm16(a1, Dl1, yy);
        x  = mm16(c0, Th0, x);   yy = mm16(c1, Th1, yy);
        x  = mm16(c0, Tl0, x);   yy = mm16(c1, Tl1, yy);
        f32x4 G = x + yy;          // G at logical (c, r0+rg)
        local = wu_[0] * G[0] + wu_[1] * G[1] + wu_[2] * G[2] + wu_[3] * G[3];
    }
#pragma unroll
    for (int off = 32; off > 0; off >>= 1) local += __shfl_down(local, off);
    if (lane == 0) red[wid] = local;
    __syncthreads();
    float total = 0.f;
#pragma unroll
    for (int w = 0; w < TPB / 64; ++w) total += red[w];

    // ---- cross-block finish: parallel flag poll in block 0 ----
    if (b != 0) {
        if (t == 0) {
            __hip_atomic_store(&parts[b], total, __ATOMIC_RELAXED,
                               __HIP_MEMORY_SCOPE_AGENT);
            __hip_atomic_store(&flags[b], FLAG_MAGIC, __ATOMIC_RELEASE,
                               __HIP_MEMORY_SCOPE_AGENT);
        }
    } else if (wid == 0) {
        float pv = 0.f;
        if (lane >= 1 && lane < 16) {
            while (__hip_atomic_load(&flags[lane], __ATOMIC_ACQUIRE,
                                     __HIP_MEMORY_SCOPE_AGENT) != FLAG_MAGIC) { }
            pv = __hip_atomic_load(&parts[lane], __ATOMIC_RELAXED,
                                   __HIP_MEMORY_SCOPE_AGENT);
        }
        if (lane == 0) pv = total;
#pragma unroll
        for (int off = 8; off > 0; off >>= 1) pv += __shfl_down(pv, off);
        if (lane == 0) out[0] = pv * (1.0f / 16.0f);
    }
}

extern "C" void kernel_launch(void* const* d_in, const int* in_sizes, int n_in,
                              void* d_out, int out_size, void* d_ws, size_t ws_size,
                              hipStream_t stream)
{
    (void)in_sizes; (void)n_in; (void)ws_size; (void)out_size;
    const float* y  = (const float*)d_in[0];
    const float* yt = (const float*)d_in[1];
    unsigned* flags = (unsigned*)d_ws;             // ws[0..15]  (0xAA-poisoned)
    float*    parts = (float*)d_ws + 16;           // ws[16..31]
    float*    out   = (float*)d_out;

    sinkhorn_kernel<<<16, TPB, 0, stream>>>(y, yt, flags, parts, out);
}